// Round 1
// baseline (1010.154 us; speedup 1.0000x reference)
//
#include <hip/hip_runtime.h>
#include <math.h>

#define NUM_A 90
#define RBINS 727      // 2*363 + 1
#define HDIM  256
#define WDIM  256

// ---------------- transpose: maskT[b][x][y] = mask[b][y][x] ----------------
__global__ __launch_bounds__(256) void transpose_k(const float* __restrict__ in,
                                                   float* __restrict__ out) {
    __shared__ float tile[32][33];
    int b = blockIdx.z;
    const float* ib = in  + (size_t)b * (HDIM * WDIM);
    float*       ob = out + (size_t)b * (HDIM * WDIM);
    int x0 = blockIdx.x * 32, y0 = blockIdx.y * 32;
    int tx = threadIdx.x, ty = threadIdx.y;
#pragma unroll
    for (int j = ty; j < 32; j += 8)
        tile[j][tx] = ib[(size_t)(y0 + j) * WDIM + (x0 + tx)];
    __syncthreads();
#pragma unroll
    for (int j = ty; j < 32; j += 8)
        ob[(size_t)(x0 + j) * HDIM + (y0 + tx)] = tile[tx][j];
}

// ---------------- soft hough: one block per (b, angle) ----------------
__global__ __launch_bounds__(256) void hough_k(const float* __restrict__ mask,
                                               const float* __restrict__ maskT,
                                               int hasT,
                                               float* __restrict__ out) {
    int blk = blockIdx.x;
    int b = blk / NUM_A;
    int a = blk - b * NUM_A;

    // thetas = linspace(0, pi*(1-1/90), 90) -> theta_a = a*pi/90
    double th = (double)a * (3.14159265358979323846 / 90.0);
    float c = (float)cos(th);
    float s = (float)sin(th);

    // Pick sweep orientation so that the fast (per-lane) coordinate has the
    // larger coefficient -> per-lane bin stride >= 0.707; with 4 px/lane the
    // lane-to-lane stride is >= 2.83 bins: conflict-free LDS atomics.
    // rho = fl(x*c) + fl(y*s); IEEE add is commutative, so the swapped sweep
    // is bit-identical to the reference order.
    const float* src;
    float cf, cs;  // fast-coeff, slow-coeff
    if (hasT && fabsf(s) > fabsf(c)) {
        src = maskT + (size_t)b * (HDIM * WDIM);
        cf = s; cs = c;          // fast coord = y, slow coord = x
    } else {
        src = mask + (size_t)b * (HDIM * WDIM);
        cf = c; cs = s;          // fast coord = x, slow coord = y
    }

    // per-wave private histograms: 4 waves x 728 f32 = 11648 B LDS
    __shared__ float hist[4][RBINS + 1];
    for (int i = threadIdx.x; i < 4 * (RBINS + 1); i += 256)
        (&hist[0][0])[i] = 0.0f;
    __syncthreads();

    int wid  = threadIdx.x >> 6;
    int lane = threadIdx.x & 63;
    float* h = hist[wid];
    int f0 = lane * 4;

    for (int r = wid; r < 256; r += 4) {
        float ps = __fmul_rn((float)(r - 128), cs);
        float4 m4 = *reinterpret_cast<const float4*>(src + (size_t)r * 256 + f0);
#pragma unroll
        for (int k = 0; k < 4; ++k) {
            float pf  = __fmul_rn((float)(f0 + k - 128), cf);
            float rho = __fadd_rn(pf, ps);
            // t = ((rho + 363) / 726) * 726, exact ref op order (RN, no FMA)
            float t = __fmul_rn(__fdiv_rn(__fadd_rn(rho, 363.0f), 726.0f), 726.0f);
            int   fl = (int)t;               // truncation, matches astype(int32)
            float fr = __fsub_rn(t, (float)fl);
            float m  = (k == 0) ? m4.x : (k == 1) ? m4.y : (k == 2) ? m4.z : m4.w;
            float wc = __fmul_rn(fr, m);
            float wf = __fmul_rn(__fsub_rn(1.0f, fr), m);
            atomicAdd(&h[fl],     wf);
            atomicAdd(&h[fl + 1], wc);
        }
    }
    __syncthreads();

    // reduce 4 wave-private histograms, coalesced store
    float* o = out + (size_t)blk * RBINS;
    for (int i = threadIdx.x; i < RBINS; i += 256)
        o[i] = (hist[0][i] + hist[1][i]) + (hist[2][i] + hist[3][i]);
}

extern "C" void kernel_launch(void* const* d_in, const int* in_sizes, int n_in,
                              void* d_out, int out_size, void* d_ws, size_t ws_size,
                              hipStream_t stream) {
    const float* mask = (const float*)d_in[0];
    float* out = (float*)d_out;
    int B = in_sizes[0] / (HDIM * WDIM);   // 16

    size_t needT = (size_t)B * HDIM * WDIM * sizeof(float);
    int hasT = (d_ws != nullptr && ws_size >= needT) ? 1 : 0;
    float* maskT = (float*)d_ws;

    if (hasT) {
        transpose_k<<<dim3(WDIM / 32, HDIM / 32, B), dim3(32, 8), 0, stream>>>(mask, maskT);
    }
    hough_k<<<B * NUM_A, 256, 0, stream>>>(mask, maskT, hasT, out);
}

// Round 2
// 1009.977 us; speedup vs baseline: 1.0002x; 1.0002x over previous
//
#include <hip/hip_runtime.h>
#include <math.h>
#include <stdint.h>

#define NUM_A 90
#define RBINS 727      // 2*363 + 1
#define HDIM  256
#define WDIM  256

// ---------------- transpose: maskT[b][x][y] = mask[b][y][x] ----------------
__global__ __launch_bounds__(256) void transpose_k(const float* __restrict__ in,
                                                   float* __restrict__ out) {
    __shared__ float tile[32][33];
    int b = blockIdx.z;
    const float* ib = in  + (size_t)b * (HDIM * WDIM);
    float*       ob = out + (size_t)b * (HDIM * WDIM);
    int x0 = blockIdx.x * 32, y0 = blockIdx.y * 32;
    int tx = threadIdx.x, ty = threadIdx.y;
#pragma unroll
    for (int j = ty; j < 32; j += 8)
        tile[j][tx] = ib[(size_t)(y0 + j) * WDIM + (x0 + tx)];
    __syncthreads();
#pragma unroll
    for (int j = ty; j < 32; j += 8)
        ob[(size_t)(x0 + j) * HDIM + (y0 + tx)] = tile[tx][j];
}

// ---------------- soft hough: one block per (b, angle) ----------------
__global__ __launch_bounds__(256) void hough_k(const float* __restrict__ mask,
                                               const float* __restrict__ maskT,
                                               int hasT,
                                               float* __restrict__ out) {
    int blk = blockIdx.x;
    int b = blk / NUM_A;
    int a = blk - b * NUM_A;

    // thetas = linspace(0, pi*(1-1/90), 90) -> theta_a = a*pi/90
    double th = (double)a * (3.14159265358979323846 / 90.0);
    float c = (float)cos(th);
    float s = (float)sin(th);

    // Sweep orientation: fast (per-lane) coordinate gets the larger
    // coefficient -> lane-to-lane bin stride >= 2.83 (4 px/lane): atomics
    // within a wave land on (mostly) distinct banks.
    const float* src;
    float cf, cs;  // fast-coeff, slow-coeff
    if (hasT && fabsf(s) > fabsf(c)) {
        src = maskT + (size_t)b * (HDIM * WDIM);
        cf = s; cs = c;          // fast coord = y, slow coord = x
    } else {
        src = mask + (size_t)b * (HDIM * WDIM);
        cf = c; cs = s;          // fast coord = x, slow coord = y
    }

    // per-wave private histograms: 4 waves x 728 f32 = 11648 B LDS
    __shared__ float hist[4][RBINS + 1];
    for (int i = threadIdx.x; i < 4 * (RBINS + 1); i += 256)
        (&hist[0][0])[i] = 0.0f;
    __syncthreads();

    int wid  = threadIdx.x >> 6;
    int lane = threadIdx.x & 63;
    int f0 = lane * 4;

    // Hardware LDS fp atomic: explicit as(3) byte offset + inline-asm
    // ds_add_f32 (bypasses any CAS expansion of generic-pointer atomicAdd).
    typedef __attribute__((address_space(3))) float lds_f;
    unsigned hbase = (unsigned)(unsigned long long)(lds_f*)(&hist[wid][0]);

    // fast-coordinate products are row-invariant: hoist out of the loop
    float pf[4];
#pragma unroll
    for (int k = 0; k < 4; ++k)
        pf[k] = (float)(f0 + k - 128) * cf;

    for (int r = wid; r < 256; r += 4) {
        // t = rho + 363; the ref's (x/726)*726 round-trip only perturbs t by
        // ~2e-4 and the bin contribution is continuous piecewise-linear in t,
        // so per-bin error <= (contribs/bin ~358) * 2e-4 ~ 0.07 << 3.8 thr.
        float base = (float)(r - 128) * cs + 363.0f;
        float4 m4 = *reinterpret_cast<const float4*>(src + (size_t)r * 256 + f0);
#pragma unroll
        for (int k = 0; k < 4; ++k) {
            float t  = pf[k] + base;
            int   fl = (int)t;               // t in [182, 545]: trunc == floor
            float fr = t - (float)fl;
            float m  = (k == 0) ? m4.x : (k == 1) ? m4.y : (k == 2) ? m4.z : m4.w;
            float wc = fr * m;
            float wf = m - wc;               // == (1-fr)*m up to 1 ulp
            unsigned off = hbase + ((unsigned)fl << 2);
            asm volatile("ds_add_f32 %0, %1"          :: "v"(off), "v"(wf));
            asm volatile("ds_add_f32 %0, %1 offset:4" :: "v"(off), "v"(wc));
        }
    }
    // inline-asm DS ops aren't tracked by the compiler's waitcnt insertion:
    // drain them before the barrier, then reduce.
    asm volatile("s_waitcnt lgkmcnt(0)" ::: "memory");
    __syncthreads();

    float* o = out + (size_t)blk * RBINS;
    for (int i = threadIdx.x; i < RBINS; i += 256)
        o[i] = (hist[0][i] + hist[1][i]) + (hist[2][i] + hist[3][i]);
}

extern "C" void kernel_launch(void* const* d_in, const int* in_sizes, int n_in,
                              void* d_out, int out_size, void* d_ws, size_t ws_size,
                              hipStream_t stream) {
    const float* mask = (const float*)d_in[0];
    float* out = (float*)d_out;
    int B = in_sizes[0] / (HDIM * WDIM);   // 16

    size_t needT = (size_t)B * HDIM * WDIM * sizeof(float);
    int hasT = (d_ws != nullptr && ws_size >= needT) ? 1 : 0;
    float* maskT = (float*)d_ws;

    if (hasT) {
        transpose_k<<<dim3(WDIM / 32, HDIM / 32, B), dim3(32, 8), 0, stream>>>(mask, maskT);
    }
    hough_k<<<B * NUM_A, 256, 0, stream>>>(mask, maskT, hasT, out);
}

// Round 3
// 131.288 us; speedup vs baseline: 7.6942x; 7.6928x over previous
//
#include <hip/hip_runtime.h>
#include <math.h>

#define NUM_A 90
#define RBINS 727      // 2*363 + 1
#define HDIM  256
#define WDIM  256
#define RMIN  181      // lowest bin ever touched (t >= 181.98)
#define RACT  365      // active bins: 181..545
#define TPB   384      // 6 waves

// ---------------- transpose: maskT[b][x][y] = mask[b][y][x] ----------------
__global__ __launch_bounds__(256) void transpose_k(const float* __restrict__ in,
                                                   float* __restrict__ out) {
    __shared__ float tile[32][33];
    int b = blockIdx.z;
    const float* ib = in  + (size_t)b * (HDIM * WDIM);
    float*       ob = out + (size_t)b * (HDIM * WDIM);
    int x0 = blockIdx.x * 32, y0 = blockIdx.y * 32;
    int tx = threadIdx.x, ty = threadIdx.y;
#pragma unroll
    for (int j = ty; j < 32; j += 8)
        tile[j][tx] = ib[(size_t)(y0 + j) * WDIM + (x0 + tx)];
    __syncthreads();
#pragma unroll
    for (int j = ty; j < 32; j += 8)
        ob[(size_t)(x0 + j) * HDIM + (y0 + tx)] = tile[tx][j];
}

// ---------------- gather hough: one block per (b, angle), one thread per bin --
// out[b,a,r] = sum over pixels of m * max(0, 1 - |t - r|),  t = x*c + y*s + 363
// (exactly the reference's bilinear scatter, inverted). Solve axis i has
// |ci| >= sqrt(2)/2, so the contributing i-run per row j has width
// 2/|ci| <= 2.83 -> at most 3 integer candidates, found in closed form.
// CONTIG: solve axis is the contiguous axis of src (mask for |c|>=|s|,
// maskT for |s|>|c|). The !CONTIG fallback (no workspace) strides by 256.
template<bool CONTIG>
__global__ __launch_bounds__(TPB) void hough_gather_k(const float* __restrict__ srcA,  // layout for |c|>=|s|
                                                      const float* __restrict__ srcB,  // layout for |s|>|c|
                                                      float* __restrict__ out) {
    int blk = blockIdx.x;
    int b = blk / NUM_A;
    int a = blk - b * NUM_A;

    double th = (double)a * (3.14159265358979323846 / 90.0);
    float c = (float)cos(th);
    float s = (float)sin(th);

    const float* src;
    float ci, cj;
    bool xsolve = fabsf(c) >= fabsf(s);
    if (xsolve) { src = srcA + (size_t)b * (HDIM * WDIM); ci = c; cj = s; }
    else        { src = srcB + (size_t)b * (HDIM * WDIM); ci = s; cj = c; }

    float* o = out + (size_t)blk * RBINS;
    int tid = threadIdx.x;

    // zero the never-touched bins: [0,181) and [546,727)
    for (int z = tid; z < RBINS - RACT; z += TPB) {
        int idx = (z < RMIN) ? z : z + RACT;
        o[idx] = 0.0f;
    }
    if (tid >= RACT) return;

    int   r    = RMIN + tid;
    float rf   = (float)r;
    float inv  = 1.0f / ci;
    float ainv = fabsf(inv);
    float Lc   = rf * inv + 128.0f - ainv;   // lo(j) = Lc - base*inv

    float acc = 0.0f;
#pragma unroll 4
    for (int j = 0; j < 256; ++j) {
        float base = (float)(j - 128) * cj + 363.0f;   // j-row part of t
        float lo   = Lc - base * inv;
        int   i0   = (int)ceilf(lo);
        float t    = (float)(i0 - 128) * ci + base;
        const float* row = CONTIG ? (src + (size_t)j * 256) : (src + j);
#pragma unroll
        for (int d = 0; d < 3; ++d) {
            int   i   = i0 + d;
            int   icl = min(max(i, 0), 255);
            float w   = fmaxf(1.0f - fabsf(t - rf), 0.0f);
            w = (i == icl) ? w : 0.0f;                 // out-of-image -> 0
            float m = CONTIG ? row[icl] : row[(size_t)icl * 256];
            acc = fmaf(m, w, acc);
            t += ci;
        }
    }
    o[r] = acc;
}

extern "C" void kernel_launch(void* const* d_in, const int* in_sizes, int n_in,
                              void* d_out, int out_size, void* d_ws, size_t ws_size,
                              hipStream_t stream) {
    const float* mask = (const float*)d_in[0];
    float* out = (float*)d_out;
    int B = in_sizes[0] / (HDIM * WDIM);   // 16

    size_t needT = (size_t)B * HDIM * WDIM * sizeof(float);
    int hasT = (d_ws != nullptr && ws_size >= needT) ? 1 : 0;
    float* maskT = (float*)d_ws;

    if (hasT) {
        transpose_k<<<dim3(WDIM / 32, HDIM / 32, B), dim3(32, 8), 0, stream>>>(mask, maskT);
        // srcA = mask (x contiguous), srcB = maskT (y contiguous)
        hough_gather_k<true><<<B * NUM_A, TPB, 0, stream>>>(mask, maskT, out);
    } else {
        // fallback: solve y on the natural layout (strided loads)
        hough_gather_k<false><<<B * NUM_A, TPB, 0, stream>>>(mask, mask, out);
    }
}